// Round 3
// baseline (789.593 us; speedup 1.0000x reference)
//
#include <hip/hip_runtime.h>
#include <hip/hip_bf16.h>
#include <math.h>

#define N_NODES 100000
#define N_EDGES 1600000
#define N_FEAT 75
#define HID 64
#define NUM_GRAPHS 4096
#define BN_EPS 1e-5f
#define NSLICE 64
#define NB 1563          // ceil(100000/64) buckets of 64 nodes
#define HIST_EPB 16384   // edges per histogram block

// ---------------- bf16 helpers ----------------

__device__ __forceinline__ float2 bf2_unpack(unsigned u) {
  return make_float2(__uint_as_float(u << 16), __uint_as_float(u & 0xFFFF0000u));
}
__device__ __forceinline__ unsigned bf2_pack(float a, float b) {
  unsigned ua = __float_as_uint(a); ua += 0x7FFF + ((ua >> 16) & 1);
  unsigned ub = __float_as_uint(b); ub += 0x7FFF + ((ub >> 16) & 1);
  return (ua >> 16) | (ub & 0xFFFF0000u);
}

// ---------------- setup: bucketed counting sort into CSR ----------------

// per-block LDS histogram of dst>>6, flushed with global atomics (1563*98 adds)
__global__ __launch_bounds__(256) void hist_kernel(const int* __restrict__ dst,
                                                   int* __restrict__ bcnt) {
  __shared__ int bins[NB];
  int t = threadIdx.x;
  for (int i = t; i < NB; i += 256) bins[i] = 0;
  __syncthreads();
  int start = blockIdx.x * HIST_EPB;
  int endE = min(start + HIST_EPB, N_EDGES);
  for (int i = start + t * 4; i + 4 <= endE; i += 1024) {
    int4 d = *(const int4*)&dst[i];
    atomicAdd(&bins[d.x >> 6], 1);
    atomicAdd(&bins[d.y >> 6], 1);
    atomicAdd(&bins[d.z >> 6], 1);
    atomicAdd(&bins[d.w >> 6], 1);
  }
  __syncthreads();
  for (int i = t; i < NB; i += 256) {
    int v = bins[i];
    if (v) atomicAdd(&bcnt[i], v);
  }
}

// exclusive scan over 1563 bucket counts (single block); writes base + cursor copies
__global__ __launch_bounds__(256) void bscan_kernel(const int* __restrict__ bcnt,
                                                    int* __restrict__ bucketBase,
                                                    int* __restrict__ bcur,
                                                    int* __restrict__ rowptr) {
  __shared__ int ls[256];
  int t = threadIdx.x;
  int vals[8];
  int s = 0;
  #pragma unroll
  for (int j = 0; j < 8; ++j) {
    int idx = t * 8 + j;
    int v = (idx < NB) ? bcnt[idx] : 0;
    vals[j] = v; s += v;
  }
  ls[t] = s;
  __syncthreads();
  for (int off = 1; off < 256; off <<= 1) {
    int a = (t >= off) ? ls[t - off] : 0;
    __syncthreads();
    ls[t] += a;
    __syncthreads();
  }
  int run = (t > 0) ? ls[t - 1] : 0;
  #pragma unroll
  for (int j = 0; j < 8; ++j) {
    int idx = t * 8 + j;
    if (idx < NB) { bucketBase[idx] = run; bcur[idx] = run; }
    else if (idx == NB) bucketBase[idx] = N_EDGES;
    run += vals[j];
  }
  if (t == 0) rowptr[N_NODES] = N_EDGES;
}

// scatter edges into their bucket region (write frontier = 1563 lines -> no write amp)
__global__ __launch_bounds__(256) void scatter_kernel(const int* __restrict__ src,
                                                      const int* __restrict__ dst,
                                                      int* __restrict__ bcur,
                                                      int2* __restrict__ tmpE) {
  int i = (blockIdx.x * blockDim.x + threadIdx.x) * 4;
  if (i + 4 <= N_EDGES) {
    int4 s4 = *(const int4*)&src[i];
    int4 d4 = *(const int4*)&dst[i];
    int slot;
    slot = atomicAdd(&bcur[d4.x >> 6], 1); tmpE[slot] = make_int2(s4.x, d4.x);
    slot = atomicAdd(&bcur[d4.y >> 6], 1); tmpE[slot] = make_int2(s4.y, d4.y);
    slot = atomicAdd(&bcur[d4.z >> 6], 1); tmpE[slot] = make_int2(s4.z, d4.z);
    slot = atomicAdd(&bcur[d4.w >> 6], 1); tmpE[slot] = make_int2(s4.w, d4.w);
  } else {
    for (; i < N_EDGES; ++i) {
      int s = src[i], d = dst[i];
      int slot = atomicAdd(&bcur[d >> 6], 1);
      tmpE[slot] = make_int2(s, d);
    }
  }
}

// per-bucket finalize: LDS per-node counts -> dinv, rowptr, ordered csr (stores dst in .y)
__global__ __launch_bounds__(256) void finalize_kernel(const int2* __restrict__ tmpE,
                                                       const int* __restrict__ bucketBase,
                                                       float* __restrict__ dinv,
                                                       int* __restrict__ rowptr,
                                                       int2* __restrict__ csr) {
  int b = blockIdx.x, t = threadIdx.x;
  int v0 = b << 6;
  int base = bucketBase[b], end = bucketBase[b + 1];
  __shared__ int lcnt[64];
  __shared__ int lcur[64];
  if (t < 64) lcnt[t] = 0;
  __syncthreads();
  for (int e = base + t; e < end; e += 256) atomicAdd(&lcnt[tmpE[e].y - v0], 1);
  __syncthreads();
  if (t < 64) {                 // threads 0..63 == wave 0: shfl scan is safe
    int c = lcnt[t];
    int x = c;
    #pragma unroll
    for (int off = 1; off < 64; off <<= 1) {
      int y = __shfl_up(x, off);
      if (t >= off) x += y;
    }
    int excl = x - c;
    lcur[t] = base + excl;
    int v = v0 + t;
    if (v < N_NODES) {
      dinv[v] = rsqrtf((float)c + 1.0f);
      rowptr[v] = base + excl;
    }
  }
  __syncthreads();
  for (int e = base + t; e < end; e += 256) {
    int2 p = tmpE[e];
    int slot = atomicAdd(&lcur[p.y - v0], 1);
    csr[slot] = p;              // .y still dst; wfix converts to weight
  }
}

// convert csr.y dst -> edge weight, and Ssum[v] = dinv^2 + sum of incoming weights
__global__ void wfix_kernel(int2* __restrict__ csr, const int* __restrict__ rowptr,
                            const float* __restrict__ dinv, float* __restrict__ Ssum) {
  int v = blockIdx.x * blockDim.x + threadIdx.x;
  if (v >= N_NODES) return;
  float dv = dinv[v];
  float s = dv * dv;
  int e1 = rowptr[v + 1];
  for (int e = rowptr[v]; e < e1; ++e) {
    int2 p = csr[e];
    float w = dinv[p.x] * dv;
    csr[e].y = __float_as_int(w);
    s += w;
  }
  Ssum[v] = s;
}

// ---------------- per-layer GEMM: H[N,64] = X[N,K] @ W[K,64], bf16 out ----------------

__global__ __launch_bounds__(256) void gemm_kernel(
    const float* __restrict__ X, const float* __restrict__ W,
    unsigned short* __restrict__ Hout, int K) {
  __shared__ float xs[64][81];
  __shared__ float ws[80][64];
  int t = threadIdx.x;
  int rowBase = blockIdx.x * 64;
  for (int i = t; i < K * 64; i += 256) ws[i >> 6][i & 63] = W[i];
  for (int i = t; i < 64 * K; i += 256) {
    int r = i / K, k = i - r * K;
    int row = rowBase + r;
    xs[r][k] = (row < N_NODES) ? X[(size_t)row * K + k] : 0.f;
  }
  __syncthreads();
  int ty = t >> 4, tx = t & 15;
  int r0 = ty * 4, c0 = tx * 4;
  float acc[4][4] = {};
  for (int k = 0; k < K; ++k) {
    float4 bq = *(const float4*)&ws[k][c0];
    float bv[4] = {bq.x, bq.y, bq.z, bq.w};
    float av[4] = {xs[r0][k], xs[r0 + 1][k], xs[r0 + 2][k], xs[r0 + 3][k]};
    #pragma unroll
    for (int i = 0; i < 4; ++i)
      #pragma unroll
      for (int j = 0; j < 4; ++j)
        acc[i][j] = fmaf(av[i], bv[j], acc[i][j]);
  }
  #pragma unroll
  for (int i = 0; i < 4; ++i) {
    int row = rowBase + r0 + i;
    if (row < N_NODES) {
      uint2 packed = make_uint2(bf2_pack(acc[i][0], acc[i][1]),
                                bf2_pack(acc[i][2], acc[i][3]));
      *(uint2*)&Hout[(size_t)row * HID + c0] = packed;
    }
  }
}

// ---------------- aggregation + relu + BN-stats (bf16 gathers, 8x unroll) ----------------

#define AGG_WAVES 8
#define AGG_PAIRS 4   // 8 nodes/wave, 64 nodes/block

__global__ __launch_bounds__(512) void agg_kernel(
    const unsigned short* __restrict__ H, const int2* __restrict__ csr,
    const int* __restrict__ rowptr, const float* __restrict__ S,
    const float* __restrict__ dinv, const float* __restrict__ cvec,
    const float* __restrict__ bias, float* __restrict__ Z,
    float* __restrict__ stats) {
  int t = threadIdx.x;
  int wave = t >> 6, lane = t & 63;
  int half = lane >> 5, li = lane & 31;
  int f = li * 2;
  int nodeBase = blockIdx.x * (AGG_WAVES * AGG_PAIRS * 2) + wave * (AGG_PAIRS * 2) + half;
  float2 cl = *(const float2*)&cvec[f];
  float2 bl = *(const float2*)&bias[f];
  float2 ssum = make_float2(0.f, 0.f), ssq = make_float2(0.f, 0.f);
  #pragma unroll
  for (int i = 0; i < AGG_PAIRS; ++i) {
    int v = nodeBase + 2 * i;
    if (v < N_NODES) {
      float dv = dinv[v];
      float2 hv = bf2_unpack(*(const unsigned*)&H[(size_t)v * HID + f]);
      float sc = dv * dv;
      float2 acc = make_float2(hv.x * sc, hv.y * sc);
      int e0 = rowptr[v], e1 = rowptr[v + 1];
      int e = e0;
      for (; e + 8 <= e1; e += 8) {
        int2 p0 = csr[e + 0], p1 = csr[e + 1], p2 = csr[e + 2], p3 = csr[e + 3];
        int2 p4 = csr[e + 4], p5 = csr[e + 5], p6 = csr[e + 6], p7 = csr[e + 7];
        unsigned u0 = *(const unsigned*)&H[(size_t)p0.x * HID + f];
        unsigned u1 = *(const unsigned*)&H[(size_t)p1.x * HID + f];
        unsigned u2 = *(const unsigned*)&H[(size_t)p2.x * HID + f];
        unsigned u3 = *(const unsigned*)&H[(size_t)p3.x * HID + f];
        unsigned u4 = *(const unsigned*)&H[(size_t)p4.x * HID + f];
        unsigned u5 = *(const unsigned*)&H[(size_t)p5.x * HID + f];
        unsigned u6 = *(const unsigned*)&H[(size_t)p6.x * HID + f];
        unsigned u7 = *(const unsigned*)&H[(size_t)p7.x * HID + f];
        float2 h0 = bf2_unpack(u0), h1 = bf2_unpack(u1), h2 = bf2_unpack(u2), h3 = bf2_unpack(u3);
        float2 h4 = bf2_unpack(u4), h5 = bf2_unpack(u5), h6 = bf2_unpack(u6), h7 = bf2_unpack(u7);
        float w0 = __int_as_float(p0.y), w1 = __int_as_float(p1.y);
        float w2 = __int_as_float(p2.y), w3 = __int_as_float(p3.y);
        float w4 = __int_as_float(p4.y), w5 = __int_as_float(p5.y);
        float w6 = __int_as_float(p6.y), w7 = __int_as_float(p7.y);
        acc.x = fmaf(w0, h0.x, fmaf(w1, h1.x, fmaf(w2, h2.x, fmaf(w3, h3.x, acc.x))));
        acc.y = fmaf(w0, h0.y, fmaf(w1, h1.y, fmaf(w2, h2.y, fmaf(w3, h3.y, acc.y))));
        acc.x = fmaf(w4, h4.x, fmaf(w5, h5.x, fmaf(w6, h6.x, fmaf(w7, h7.x, acc.x))));
        acc.y = fmaf(w4, h4.y, fmaf(w5, h5.y, fmaf(w6, h6.y, fmaf(w7, h7.y, acc.y))));
      }
      for (; e + 4 <= e1; e += 4) {
        int2 p0 = csr[e + 0], p1 = csr[e + 1], p2 = csr[e + 2], p3 = csr[e + 3];
        unsigned u0 = *(const unsigned*)&H[(size_t)p0.x * HID + f];
        unsigned u1 = *(const unsigned*)&H[(size_t)p1.x * HID + f];
        unsigned u2 = *(const unsigned*)&H[(size_t)p2.x * HID + f];
        unsigned u3 = *(const unsigned*)&H[(size_t)p3.x * HID + f];
        float2 h0 = bf2_unpack(u0), h1 = bf2_unpack(u1), h2 = bf2_unpack(u2), h3 = bf2_unpack(u3);
        float w0 = __int_as_float(p0.y), w1 = __int_as_float(p1.y);
        float w2 = __int_as_float(p2.y), w3 = __int_as_float(p3.y);
        acc.x = fmaf(w0, h0.x, fmaf(w1, h1.x, fmaf(w2, h2.x, fmaf(w3, h3.x, acc.x))));
        acc.y = fmaf(w0, h0.y, fmaf(w1, h1.y, fmaf(w2, h2.y, fmaf(w3, h3.y, acc.y))));
      }
      for (; e < e1; ++e) {
        int2 p = csr[e];
        float2 h = bf2_unpack(*(const unsigned*)&H[(size_t)p.x * HID + f]);
        float w = __int_as_float(p.y);
        acc.x = fmaf(w, h.x, acc.x);
        acc.y = fmaf(w, h.y, acc.y);
      }
      float sv = S[v];
      float2 z = make_float2(fmaxf(fmaf(sv, cl.x, acc.x + bl.x), 0.f),
                             fmaxf(fmaf(sv, cl.y, acc.y + bl.y), 0.f));
      *(float2*)&Z[(size_t)v * HID + f] = z;
      ssum.x += z.x; ssum.y += z.y;
      ssq.x += z.x * z.x; ssq.y += z.y * z.y;
    }
  }
  __shared__ float redS[AGG_WAVES * 2][64];
  __shared__ float redQ[AGG_WAVES * 2][64];
  redS[wave * 2 + half][f] = ssum.x;
  redS[wave * 2 + half][f + 1] = ssum.y;
  redQ[wave * 2 + half][f] = ssq.x;
  redQ[wave * 2 + half][f + 1] = ssq.y;
  __syncthreads();
  if (wave == 0) {
    float s = 0.f, q = 0.f;
    #pragma unroll
    for (int i = 0; i < AGG_WAVES * 2; ++i) { s += redS[i][lane]; q += redQ[i][lane]; }
    float* sl = stats + (size_t)(blockIdx.x & (NSLICE - 1)) * 128;
    atomicAdd(&sl[lane], s);
    atomicAdd(&sl[64 + lane], q);
  }
}

// ---------------- BN fold ----------------

__global__ __launch_bounds__(256) void prep_kernel(
    const float* __restrict__ stats, const float* __restrict__ g,
    const float* __restrict__ be, const float* __restrict__ Wnext,
    float* __restrict__ Wp, float* __restrict__ cvec,
    float* __restrict__ ab, int hasNext) {
  __shared__ float tmp[128];
  __shared__ float alpha[64];
  __shared__ float beta[64];
  int t = threadIdx.x;
  if (t < 128) {
    float s = 0.f;
    for (int i = 0; i < NSLICE; ++i) s += stats[(size_t)i * 128 + t];
    tmp[t] = s;
  }
  __syncthreads();
  if (t < 64) {
    float m = tmp[t] / (float)N_NODES;
    float var = tmp[64 + t] / (float)N_NODES - m * m;
    float a = g[t] * rsqrtf(var + BN_EPS);
    alpha[t] = a;
    float bt = be[t] - m * a;
    beta[t] = bt;
    ab[t] = a;
    ab[64 + t] = bt;
  }
  __syncthreads();
  if (hasNext) {
    for (int i = t; i < HID * HID; i += 256) Wp[i] = alpha[i >> 6] * Wnext[i];
    if (t < 64) {
      float c = 0.f;
      for (int k = 0; k < HID; ++k) c += beta[k] * Wnext[k * HID + t];
      cvec[t] = c;
    }
  }
}

// ---------------- pool ----------------

#define POOL_CH 32

__global__ __launch_bounds__(256) void pool_kernel(
    const float* __restrict__ Z, const int* __restrict__ batch,
    const float* __restrict__ ab, float* __restrict__ out) {
  int tid = blockIdx.x * blockDim.x + threadIdx.x;
  int w = tid >> 6, lane = tid & 63;
  int v0 = w * POOL_CH;
  if (v0 >= N_NODES) return;
  int v1 = min(N_NODES, v0 + POOL_CH);
  float a = ab[lane], b = ab[64 + lane];
  float acc = 0.f;
  int cur = batch[v0];
  for (int v = v0; v < v1; ++v) {
    int bg = batch[v];
    if (bg != cur) {
      atomicAdd(&out[(size_t)cur * HID + lane], acc);
      acc = 0.f;
      cur = bg;
    }
    acc = fmaf(Z[(size_t)v * HID + lane], a, acc + b);
  }
  atomicAdd(&out[(size_t)cur * HID + lane], acc);
}

// ---------------- launch ----------------

extern "C" void kernel_launch(void* const* d_in, const int* in_sizes, int n_in,
                              void* d_out, int out_size, void* d_ws, size_t ws_size,
                              hipStream_t stream) {
  const float* x    = (const float*)d_in[0];
  const int* src    = (const int*)d_in[1];
  const int* dst    = (const int*)d_in[2];
  const int* batch  = (const int*)d_in[3];
  const float* W[4]  = {(const float*)d_in[4], (const float*)d_in[8],
                        (const float*)d_in[12], (const float*)d_in[16]};
  const float* b[4]  = {(const float*)d_in[5], (const float*)d_in[9],
                        (const float*)d_in[13], (const float*)d_in[17]};
  const float* g[4]  = {(const float*)d_in[6], (const float*)d_in[10],
                        (const float*)d_in[14], (const float*)d_in[18]};
  const float* be[4] = {(const float*)d_in[7], (const float*)d_in[11],
                        (const float*)d_in[15], (const float*)d_in[19]};

  char* wsb = (char*)d_ws;
  size_t off = 0;
  auto alloc = [&](size_t bytes) -> void* {
    void* p = wsb + off;
    off += (bytes + 255) & ~(size_t)255;
    return p;
  };
  // zeroed region (one memset)
  int*   bcnt   = (int*)  alloc((size_t)NB * 4);
  float* c0     = (float*)alloc(64 * 4);
  float* stats  = (float*)alloc((size_t)4 * NSLICE * 128 * 4);
  size_t zero_bytes = off;
  // non-zeroed
  int*   bucketBase = (int*)alloc((size_t)(NB + 1) * 4);
  int*   bcur   = (int*)  alloc((size_t)NB * 4);
  float* Ssum   = (float*)alloc((size_t)N_NODES * 4);
  int*   rowptr = (int*)  alloc((size_t)(N_NODES + 1) * 4);
  float* dinv   = (float*)alloc((size_t)N_NODES * 4);
  int2*  tmpE   = (int2*) alloc((size_t)N_EDGES * 8);
  int2*  csr    = (int2*) alloc((size_t)N_EDGES * 8);
  unsigned short* Hb = (unsigned short*)alloc((size_t)N_NODES * HID * 2);
  float* Zb     = (float*)alloc((size_t)N_NODES * HID * 4);
  float* Wp     = (float*)alloc(HID * HID * 4);
  float* cv     = (float*)alloc(64 * 4);
  float* ab     = (float*)alloc(128 * 4);

  hipMemsetAsync(d_ws, 0, zero_bytes, stream);
  hipMemsetAsync(d_out, 0, (size_t)out_size * 4, stream);

  hist_kernel<<<(N_EDGES + HIST_EPB - 1) / HIST_EPB, 256, 0, stream>>>(dst, bcnt);
  bscan_kernel<<<1, 256, 0, stream>>>(bcnt, bucketBase, bcur, rowptr);
  scatter_kernel<<<(N_EDGES / 4 + 255) / 256, 256, 0, stream>>>(src, dst, bcur, tmpE);
  finalize_kernel<<<NB, 256, 0, stream>>>(tmpE, bucketBase, dinv, rowptr, csr);
  wfix_kernel<<<(N_NODES + 255) / 256, 256, 0, stream>>>(csr, rowptr, dinv, Ssum);

  int gemmBlocks = (N_NODES + 63) / 64;
  int aggBlocks  = (N_NODES + AGG_WAVES * AGG_PAIRS * 2 - 1) / (AGG_WAVES * AGG_PAIRS * 2);

  // layer 1 (K=75, c=0)
  gemm_kernel<<<gemmBlocks, 256, 0, stream>>>(x, W[0], Hb, N_FEAT);
  agg_kernel<<<aggBlocks, 512, 0, stream>>>(Hb, csr, rowptr, Ssum, dinv, c0, b[0], Zb, stats);
  prep_kernel<<<1, 256, 0, stream>>>(stats, g[0], be[0], W[1], Wp, cv, ab, 1);

  // layers 2..4
  for (int l = 1; l < 4; ++l) {
    gemm_kernel<<<gemmBlocks, 256, 0, stream>>>(Zb, Wp, Hb, HID);
    agg_kernel<<<aggBlocks, 512, 0, stream>>>(Hb, csr, rowptr, Ssum, dinv, cv, b[l], Zb,
                                              stats + (size_t)l * NSLICE * 128);
    prep_kernel<<<1, 256, 0, stream>>>(stats + (size_t)l * NSLICE * 128, g[l], be[l],
                                       (l < 3) ? W[l + 1] : nullptr, Wp, cv, ab,
                                       (l < 3) ? 1 : 0);
  }

  int poolBlocks = (N_NODES + 4 * POOL_CH - 1) / (4 * POOL_CH);
  pool_kernel<<<poolBlocks, 256, 0, stream>>>(Zb, batch, ab, (float*)d_out);
}

// Round 4
// 672.363 us; speedup vs baseline: 1.1744x; 1.1744x over previous
//
#include <hip/hip_runtime.h>
#include <hip/hip_bf16.h>
#include <math.h>

#define N_NODES 100000
#define N_EDGES 1600000
#define N_FEAT 75
#define HID 64
#define NUM_GRAPHS 4096
#define BN_EPS 1e-5f
#define NSLICE 64

// ---------------- bf16 helpers ----------------

__device__ __forceinline__ unsigned bf2_pack(float a, float b) {
  unsigned ua = __float_as_uint(a); ua += 0x7FFF + ((ua >> 16) & 1);
  unsigned ub = __float_as_uint(b); ub += 0x7FFF + ((ub >> 16) & 1);
  return (ua >> 16) | (ub & 0xFFFF0000u);
}
__device__ __forceinline__ float4 bf4_unpack(uint2 u) {
  return make_float4(__uint_as_float(u.x << 16), __uint_as_float(u.x & 0xFFFF0000u),
                     __uint_as_float(u.y << 16), __uint_as_float(u.y & 0xFFFF0000u));
}

// ---------------- setup: degree, norms, CSR build (src-only entries) ----------------

__global__ void count_kernel(const int* __restrict__ dst, int* __restrict__ cnt) {
  int i = (blockIdx.x * blockDim.x + threadIdx.x) * 4;
  if (i + 4 <= N_EDGES) {
    int4 d = *(const int4*)&dst[i];
    atomicAdd(&cnt[d.x], 1);
    atomicAdd(&cnt[d.y], 1);
    atomicAdd(&cnt[d.z], 1);
    atomicAdd(&cnt[d.w], 1);
  } else {
    for (; i < N_EDGES; ++i) atomicAdd(&cnt[dst[i]], 1);
  }
}

__global__ void dinv_kernel(const int* __restrict__ cnt, float* __restrict__ dinv) {
  int v = blockIdx.x * blockDim.x + threadIdx.x;
  if (v < N_NODES) dinv[v] = rsqrtf((float)cnt[v] + 1.0f);
}

// exclusive scan of cnt[0..N) into rowptr[0..N); 1024 elems/block
__global__ void scan1_kernel(const int* __restrict__ in, int* __restrict__ out,
                             int* __restrict__ bsum) {
  __shared__ int ls[256];
  int t = threadIdx.x;
  int base = blockIdx.x * 1024 + t * 4;
  int a0 = (base + 0 < N_NODES) ? in[base + 0] : 0;
  int a1 = (base + 1 < N_NODES) ? in[base + 1] : 0;
  int a2 = (base + 2 < N_NODES) ? in[base + 2] : 0;
  int a3 = (base + 3 < N_NODES) ? in[base + 3] : 0;
  ls[t] = a0 + a1 + a2 + a3;
  __syncthreads();
  for (int off = 1; off < 256; off <<= 1) {
    int add = (t >= off) ? ls[t - off] : 0;
    __syncthreads();
    ls[t] += add;
    __syncthreads();
  }
  int excl = (t > 0) ? ls[t - 1] : 0;
  if (base + 0 < N_NODES) out[base + 0] = excl;
  if (base + 1 < N_NODES) out[base + 1] = excl + a0;
  if (base + 2 < N_NODES) out[base + 2] = excl + a0 + a1;
  if (base + 3 < N_NODES) out[base + 3] = excl + a0 + a1 + a2;
  if (t == 255) bsum[blockIdx.x] = ls[255];
}

__global__ void scan2_kernel(int* bsum, int nb) {
  if (threadIdx.x == 0 && blockIdx.x == 0) {
    int a = 0;
    for (int i = 0; i < nb; ++i) { int v = bsum[i]; bsum[i] = a; a += v; }
  }
}

// finalize rowptr AND initialize pos=rowptr
__global__ void scan3_kernel(int* __restrict__ out, const int* __restrict__ bsum,
                             int* __restrict__ pos) {
  int t = threadIdx.x;
  int base = blockIdx.x * 1024 + t * 4;
  int add = bsum[blockIdx.x];
  #pragma unroll
  for (int i = 0; i < 4; ++i)
    if (base + i < N_NODES) {
      int v = out[base + i] + add;
      out[base + i] = v;
      pos[base + i] = v;
    }
  if (blockIdx.x == 0 && t == 0) out[N_NODES] = N_EDGES;
}

// scatter edges into CSR slots: 4 B src-index entries only
__global__ void fill_kernel(const int* __restrict__ src, const int* __restrict__ dst,
                            int* __restrict__ pos, int* __restrict__ csr) {
  int i = (blockIdx.x * blockDim.x + threadIdx.x) * 4;
  if (i + 4 <= N_EDGES) {
    int4 s4 = *(const int4*)&src[i];
    int4 d4 = *(const int4*)&dst[i];
    int p;
    p = atomicAdd(&pos[d4.x], 1); csr[p] = s4.x;
    p = atomicAdd(&pos[d4.y], 1); csr[p] = s4.y;
    p = atomicAdd(&pos[d4.z], 1); csr[p] = s4.z;
    p = atomicAdd(&pos[d4.w], 1); csr[p] = s4.w;
  } else {
    for (; i < N_EDGES; ++i) {
      int p = atomicAdd(&pos[dst[i]], 1);
      csr[p] = src[i];
    }
  }
}

// S[v] = dv*(dv + sum of dinv[src]) == dv^2 + sum of edge weights
__global__ void ssum_kernel(const int* __restrict__ csr, const int* __restrict__ rowptr,
                            const float* __restrict__ dinv, float* __restrict__ Ssum) {
  int v = blockIdx.x * blockDim.x + threadIdx.x;
  if (v >= N_NODES) return;
  float dv = dinv[v];
  float s = dv;
  int e1 = rowptr[v + 1];
  for (int e = rowptr[v]; e < e1; ++e) s += dinv[csr[e]];
  Ssum[v] = dv * s;
}

// ---------------- per-layer GEMM: Hs[N,64] = dinv ⊙ (X[N,K] @ W[K,64]), bf16 out --------

__global__ __launch_bounds__(256) void gemm_kernel(
    const float* __restrict__ X, const float* __restrict__ W,
    const float* __restrict__ dinv, unsigned short* __restrict__ Hout, int K) {
  __shared__ float xs[64][81];
  __shared__ float ws[80][64];
  int t = threadIdx.x;
  int rowBase = blockIdx.x * 64;
  for (int i = t; i < K * 64; i += 256) ws[i >> 6][i & 63] = W[i];
  for (int i = t; i < 64 * K; i += 256) {
    int r = i / K, k = i - r * K;
    int row = rowBase + r;
    xs[r][k] = (row < N_NODES) ? X[(size_t)row * K + k] : 0.f;
  }
  __syncthreads();
  int ty = t >> 4, tx = t & 15;
  int r0 = ty * 4, c0 = tx * 4;
  float acc[4][4] = {};
  for (int k = 0; k < K; ++k) {
    float4 bq = *(const float4*)&ws[k][c0];
    float bv[4] = {bq.x, bq.y, bq.z, bq.w};
    float av[4] = {xs[r0][k], xs[r0 + 1][k], xs[r0 + 2][k], xs[r0 + 3][k]};
    #pragma unroll
    for (int i = 0; i < 4; ++i)
      #pragma unroll
      for (int j = 0; j < 4; ++j)
        acc[i][j] = fmaf(av[i], bv[j], acc[i][j]);
  }
  #pragma unroll
  for (int i = 0; i < 4; ++i) {
    int row = rowBase + r0 + i;
    if (row < N_NODES) {
      float dv = dinv[row];
      uint2 packed = make_uint2(bf2_pack(acc[i][0] * dv, acc[i][1] * dv),
                                bf2_pack(acc[i][2] * dv, acc[i][3] * dv));
      *(uint2*)&Hout[(size_t)row * HID + c0] = packed;
    }
  }
}

// ---------------- aggregation + relu + BN-stats ----------------
// z[v] = relu( dv*(Hs[v] + sum_in Hs[src]) + S[v]*c + b );  stats += (z, z^2)
// 4 feats/lane (uint2 = 4 bf16), 4 nodes/wave, 8x edge unroll

#define AGG_WAVES 8
#define AGG_NPN 2   // node iterations per quarter -> 64 nodes/block

__global__ __launch_bounds__(512) void agg_kernel(
    const unsigned short* __restrict__ Hs, const int* __restrict__ csr,
    const int* __restrict__ rowptr, const float* __restrict__ S,
    const float* __restrict__ dinv, const float* __restrict__ cvec,
    const float* __restrict__ bias, float* __restrict__ Z,
    float* __restrict__ stats) {
  int t = threadIdx.x;
  int wave = t >> 6, lane = t & 63;
  int q = lane >> 4, li = lane & 15;
  int f = li * 4;
  int nodeBase = blockIdx.x * (AGG_WAVES * 4 * AGG_NPN) + wave * (4 * AGG_NPN) + q;
  float4 cl = *(const float4*)&cvec[f];
  float4 bl = *(const float4*)&bias[f];
  float4 ssum = make_float4(0.f, 0.f, 0.f, 0.f);
  float4 ssq  = make_float4(0.f, 0.f, 0.f, 0.f);
  #pragma unroll
  for (int it = 0; it < AGG_NPN; ++it) {
    int v = nodeBase + 4 * it;
    if (v < N_NODES) {
      uint2 uv = *(const uint2*)&Hs[(size_t)v * HID + f];
      float4 acc = bf4_unpack(uv);
      int e0 = rowptr[v], e1 = rowptr[v + 1];
      int e = e0;
      for (; e + 8 <= e1; e += 8) {
        int s0 = csr[e + 0], s1 = csr[e + 1], s2 = csr[e + 2], s3 = csr[e + 3];
        int s4 = csr[e + 4], s5 = csr[e + 5], s6 = csr[e + 6], s7 = csr[e + 7];
        uint2 u0 = *(const uint2*)&Hs[(size_t)s0 * HID + f];
        uint2 u1 = *(const uint2*)&Hs[(size_t)s1 * HID + f];
        uint2 u2 = *(const uint2*)&Hs[(size_t)s2 * HID + f];
        uint2 u3 = *(const uint2*)&Hs[(size_t)s3 * HID + f];
        uint2 u4 = *(const uint2*)&Hs[(size_t)s4 * HID + f];
        uint2 u5 = *(const uint2*)&Hs[(size_t)s5 * HID + f];
        uint2 u6 = *(const uint2*)&Hs[(size_t)s6 * HID + f];
        uint2 u7 = *(const uint2*)&Hs[(size_t)s7 * HID + f];
        float4 h0 = bf4_unpack(u0), h1 = bf4_unpack(u1);
        float4 h2 = bf4_unpack(u2), h3 = bf4_unpack(u3);
        float4 h4 = bf4_unpack(u4), h5 = bf4_unpack(u5);
        float4 h6 = bf4_unpack(u6), h7 = bf4_unpack(u7);
        acc.x += (h0.x + h1.x) + (h2.x + h3.x) + (h4.x + h5.x) + (h6.x + h7.x);
        acc.y += (h0.y + h1.y) + (h2.y + h3.y) + (h4.y + h5.y) + (h6.y + h7.y);
        acc.z += (h0.z + h1.z) + (h2.z + h3.z) + (h4.z + h5.z) + (h6.z + h7.z);
        acc.w += (h0.w + h1.w) + (h2.w + h3.w) + (h4.w + h5.w) + (h6.w + h7.w);
      }
      for (; e + 2 <= e1; e += 2) {
        int s0 = csr[e + 0], s1 = csr[e + 1];
        uint2 u0 = *(const uint2*)&Hs[(size_t)s0 * HID + f];
        uint2 u1 = *(const uint2*)&Hs[(size_t)s1 * HID + f];
        float4 h0 = bf4_unpack(u0), h1 = bf4_unpack(u1);
        acc.x += h0.x + h1.x;
        acc.y += h0.y + h1.y;
        acc.z += h0.z + h1.z;
        acc.w += h0.w + h1.w;
      }
      if (e < e1) {
        int s0 = csr[e];
        float4 h0 = bf4_unpack(*(const uint2*)&Hs[(size_t)s0 * HID + f]);
        acc.x += h0.x; acc.y += h0.y; acc.z += h0.z; acc.w += h0.w;
      }
      float dv = dinv[v], sv = S[v];
      float4 z;
      z.x = fmaxf(fmaf(dv, acc.x, fmaf(sv, cl.x, bl.x)), 0.f);
      z.y = fmaxf(fmaf(dv, acc.y, fmaf(sv, cl.y, bl.y)), 0.f);
      z.z = fmaxf(fmaf(dv, acc.z, fmaf(sv, cl.z, bl.z)), 0.f);
      z.w = fmaxf(fmaf(dv, acc.w, fmaf(sv, cl.w, bl.w)), 0.f);
      *(float4*)&Z[(size_t)v * HID + f] = z;
      ssum.x += z.x; ssum.y += z.y; ssum.z += z.z; ssum.w += z.w;
      ssq.x += z.x * z.x; ssq.y += z.y * z.y; ssq.z += z.z * z.z; ssq.w += z.w * z.w;
    }
  }
  // reduce across the 4 quarters (same feats) via shuffles, then LDS across waves
  #pragma unroll
  for (int m = 16; m <= 32; m <<= 1) {
    ssum.x += __shfl_xor(ssum.x, m); ssum.y += __shfl_xor(ssum.y, m);
    ssum.z += __shfl_xor(ssum.z, m); ssum.w += __shfl_xor(ssum.w, m);
    ssq.x  += __shfl_xor(ssq.x,  m); ssq.y  += __shfl_xor(ssq.y,  m);
    ssq.z  += __shfl_xor(ssq.z,  m); ssq.w  += __shfl_xor(ssq.w,  m);
  }
  __shared__ float redS[AGG_WAVES][64];
  __shared__ float redQ[AGG_WAVES][64];
  if (q == 0) {
    *(float4*)&redS[wave][f] = ssum;
    *(float4*)&redQ[wave][f] = ssq;
  }
  __syncthreads();
  if (wave == 0) {
    float s = 0.f, qq = 0.f;
    #pragma unroll
    for (int i = 0; i < AGG_WAVES; ++i) { s += redS[i][lane]; qq += redQ[i][lane]; }
    float* sl = stats + (size_t)(blockIdx.x & (NSLICE - 1)) * 128;
    atomicAdd(&sl[lane], s);
    atomicAdd(&sl[64 + lane], qq);
  }
}

// ---------------- BN fold ----------------

__global__ __launch_bounds__(256) void prep_kernel(
    const float* __restrict__ stats, const float* __restrict__ g,
    const float* __restrict__ be, const float* __restrict__ Wnext,
    float* __restrict__ Wp, float* __restrict__ cvec,
    float* __restrict__ ab, int hasNext) {
  __shared__ float tmp[128];
  __shared__ float alpha[64];
  __shared__ float beta[64];
  int t = threadIdx.x;
  if (t < 128) {
    float s = 0.f;
    for (int i = 0; i < NSLICE; ++i) s += stats[(size_t)i * 128 + t];
    tmp[t] = s;
  }
  __syncthreads();
  if (t < 64) {
    float m = tmp[t] / (float)N_NODES;
    float var = tmp[64 + t] / (float)N_NODES - m * m;
    float a = g[t] * rsqrtf(var + BN_EPS);
    alpha[t] = a;
    float bt = be[t] - m * a;
    beta[t] = bt;
    ab[t] = a;
    ab[64 + t] = bt;
  }
  __syncthreads();
  if (hasNext) {
    for (int i = t; i < HID * HID; i += 256) Wp[i] = alpha[i >> 6] * Wnext[i];
    if (t < 64) {
      float c = 0.f;
      for (int k = 0; k < HID; ++k) c += beta[k] * Wnext[k * HID + t];
      cvec[t] = c;
    }
  }
}

// ---------------- pool ----------------

#define POOL_CH 32

__global__ __launch_bounds__(256) void pool_kernel(
    const float* __restrict__ Z, const int* __restrict__ batch,
    const float* __restrict__ ab, float* __restrict__ out) {
  int tid = blockIdx.x * blockDim.x + threadIdx.x;
  int w = tid >> 6, lane = tid & 63;
  int v0 = w * POOL_CH;
  if (v0 >= N_NODES) return;
  int v1 = min(N_NODES, v0 + POOL_CH);
  float a = ab[lane], b = ab[64 + lane];
  float acc = 0.f;
  int cur = batch[v0];
  for (int v = v0; v < v1; ++v) {
    int bg = batch[v];
    if (bg != cur) {
      atomicAdd(&out[(size_t)cur * HID + lane], acc);
      acc = 0.f;
      cur = bg;
    }
    acc = fmaf(Z[(size_t)v * HID + lane], a, acc + b);
  }
  atomicAdd(&out[(size_t)cur * HID + lane], acc);
}

// ---------------- launch ----------------

extern "C" void kernel_launch(void* const* d_in, const int* in_sizes, int n_in,
                              void* d_out, int out_size, void* d_ws, size_t ws_size,
                              hipStream_t stream) {
  const float* x    = (const float*)d_in[0];
  const int* src    = (const int*)d_in[1];
  const int* dst    = (const int*)d_in[2];
  const int* batch  = (const int*)d_in[3];
  const float* W[4]  = {(const float*)d_in[4], (const float*)d_in[8],
                        (const float*)d_in[12], (const float*)d_in[16]};
  const float* b[4]  = {(const float*)d_in[5], (const float*)d_in[9],
                        (const float*)d_in[13], (const float*)d_in[17]};
  const float* g[4]  = {(const float*)d_in[6], (const float*)d_in[10],
                        (const float*)d_in[14], (const float*)d_in[18]};
  const float* be[4] = {(const float*)d_in[7], (const float*)d_in[11],
                        (const float*)d_in[15], (const float*)d_in[19]};

  char* wsb = (char*)d_ws;
  size_t off = 0;
  auto alloc = [&](size_t bytes) -> void* {
    void* p = wsb + off;
    off += (bytes + 255) & ~(size_t)255;
    return p;
  };
  // zeroed region (one memset)
  int*   cnt    = (int*)  alloc((size_t)(N_NODES + 1) * 4);
  float* c0     = (float*)alloc(64 * 4);
  float* stats  = (float*)alloc((size_t)4 * NSLICE * 128 * 4);
  size_t zero_bytes = off;
  // non-zeroed
  float* Ssum   = (float*)alloc((size_t)N_NODES * 4);
  int*   rowptr = (int*)  alloc((size_t)(N_NODES + 1) * 4);
  int*   pos    = (int*)  alloc((size_t)N_NODES * 4);
  int*   bsum   = (int*)  alloc(128 * 4);
  float* dinv   = (float*)alloc((size_t)N_NODES * 4);
  int*   csr    = (int*)  alloc((size_t)N_EDGES * 4);
  unsigned short* Hb = (unsigned short*)alloc((size_t)N_NODES * HID * 2);
  float* Zb     = (float*)alloc((size_t)N_NODES * HID * 4);
  float* Wp     = (float*)alloc(HID * HID * 4);
  float* cv     = (float*)alloc(64 * 4);
  float* ab     = (float*)alloc(128 * 4);

  hipMemsetAsync(d_ws, 0, zero_bytes, stream);
  hipMemsetAsync(d_out, 0, (size_t)out_size * 4, stream);

  count_kernel<<<(N_EDGES / 4 + 255) / 256, 256, 0, stream>>>(dst, cnt);
  dinv_kernel<<<(N_NODES + 255) / 256, 256, 0, stream>>>(cnt, dinv);
  int nscan = (N_NODES + 1023) / 1024;
  scan1_kernel<<<nscan, 256, 0, stream>>>(cnt, rowptr, bsum);
  scan2_kernel<<<1, 64, 0, stream>>>(bsum, nscan);
  scan3_kernel<<<nscan, 256, 0, stream>>>(rowptr, bsum, pos);
  fill_kernel<<<(N_EDGES / 4 + 255) / 256, 256, 0, stream>>>(src, dst, pos, csr);
  ssum_kernel<<<(N_NODES + 255) / 256, 256, 0, stream>>>(csr, rowptr, dinv, Ssum);

  int gemmBlocks = (N_NODES + 63) / 64;
  int nodesPerAggBlock = AGG_WAVES * 4 * AGG_NPN;
  int aggBlocks = (N_NODES + nodesPerAggBlock - 1) / nodesPerAggBlock;

  // layer 1 (K=75, c=0)
  gemm_kernel<<<gemmBlocks, 256, 0, stream>>>(x, W[0], dinv, Hb, N_FEAT);
  agg_kernel<<<aggBlocks, 512, 0, stream>>>(Hb, csr, rowptr, Ssum, dinv, c0, b[0], Zb, stats);
  prep_kernel<<<1, 256, 0, stream>>>(stats, g[0], be[0], W[1], Wp, cv, ab, 1);

  // layers 2..4
  for (int l = 1; l < 4; ++l) {
    gemm_kernel<<<gemmBlocks, 256, 0, stream>>>(Zb, Wp, dinv, Hb, HID);
    agg_kernel<<<aggBlocks, 512, 0, stream>>>(Hb, csr, rowptr, Ssum, dinv, cv, b[l], Zb,
                                              stats + (size_t)l * NSLICE * 128);
    prep_kernel<<<1, 256, 0, stream>>>(stats + (size_t)l * NSLICE * 128, g[l], be[l],
                                       (l < 3) ? W[l + 1] : nullptr, Wp, cv, ab,
                                       (l < 3) ? 1 : 0);
  }

  int poolBlocks = (N_NODES + 4 * POOL_CH - 1) / (4 * POOL_CH);
  pool_kernel<<<poolBlocks, 256, 0, stream>>>(Zb, batch, ab, (float*)d_out);
}

// Round 6
// 628.639 us; speedup vs baseline: 1.2560x; 1.0696x over previous
//
#include <hip/hip_runtime.h>
#include <hip/hip_bf16.h>
#include <math.h>

#define N_NODES 100000
#define N_EDGES 1600000
#define N_FEAT 75
#define HID 64
#define NUM_GRAPHS 4096
#define BN_EPS 1e-5f
#define NSLICE 64

typedef int v4i __attribute__((ext_vector_type(4)));   // native vector for nontemporal builtins

// ---------------- bf16 helpers ----------------

__device__ __forceinline__ unsigned bf2_pack(float a, float b) {
  unsigned ua = __float_as_uint(a); ua += 0x7FFF + ((ua >> 16) & 1);
  unsigned ub = __float_as_uint(b); ub += 0x7FFF + ((ub >> 16) & 1);
  return (ua >> 16) | (ub & 0xFFFF0000u);
}
__device__ __forceinline__ float4 bf4_unpack(uint2 u) {
  return make_float4(__uint_as_float(u.x << 16), __uint_as_float(u.x & 0xFFFF0000u),
                     __uint_as_float(u.y << 16), __uint_as_float(u.y & 0xFFFF0000u));
}

// ---------------- setup: degree, norms, CSR build (src-only entries) ----------------

__global__ void count_kernel(const int* __restrict__ dst, int* __restrict__ cnt) {
  int i = (blockIdx.x * blockDim.x + threadIdx.x) * 4;
  if (i + 4 <= N_EDGES) {
    int4 d = *(const int4*)&dst[i];
    atomicAdd(&cnt[d.x], 1);
    atomicAdd(&cnt[d.y], 1);
    atomicAdd(&cnt[d.z], 1);
    atomicAdd(&cnt[d.w], 1);
  } else {
    for (; i < N_EDGES; ++i) atomicAdd(&cnt[dst[i]], 1);
  }
}

__global__ void dinv_kernel(const int* __restrict__ cnt, float* __restrict__ dinv) {
  int v = blockIdx.x * blockDim.x + threadIdx.x;
  if (v < N_NODES) dinv[v] = rsqrtf((float)cnt[v] + 1.0f);
}

// exclusive scan of cnt[0..N) into rowptr[0..N); 1024 elems/block
__global__ void scan1_kernel(const int* __restrict__ in, int* __restrict__ out,
                             int* __restrict__ bsum) {
  __shared__ int ls[256];
  int t = threadIdx.x;
  int base = blockIdx.x * 1024 + t * 4;
  int a0 = (base + 0 < N_NODES) ? in[base + 0] : 0;
  int a1 = (base + 1 < N_NODES) ? in[base + 1] : 0;
  int a2 = (base + 2 < N_NODES) ? in[base + 2] : 0;
  int a3 = (base + 3 < N_NODES) ? in[base + 3] : 0;
  ls[t] = a0 + a1 + a2 + a3;
  __syncthreads();
  for (int off = 1; off < 256; off <<= 1) {
    int add = (t >= off) ? ls[t - off] : 0;
    __syncthreads();
    ls[t] += add;
    __syncthreads();
  }
  int excl = (t > 0) ? ls[t - 1] : 0;
  if (base + 0 < N_NODES) out[base + 0] = excl;
  if (base + 1 < N_NODES) out[base + 1] = excl + a0;
  if (base + 2 < N_NODES) out[base + 2] = excl + a0 + a1;
  if (base + 3 < N_NODES) out[base + 3] = excl + a0 + a1 + a2;
  if (t == 255) bsum[blockIdx.x] = ls[255];
}

__global__ void scan2_kernel(int* bsum, int nb) {
  if (threadIdx.x == 0 && blockIdx.x == 0) {
    int a = 0;
    for (int i = 0; i < nb; ++i) { int v = bsum[i]; bsum[i] = a; a += v; }
  }
}

// finalize rowptr AND initialize pos=rowptr
__global__ void scan3_kernel(int* __restrict__ out, const int* __restrict__ bsum,
                             int* __restrict__ pos) {
  int t = threadIdx.x;
  int base = blockIdx.x * 1024 + t * 4;
  int add = bsum[blockIdx.x];
  #pragma unroll
  for (int i = 0; i < 4; ++i)
    if (base + i < N_NODES) {
      int v = out[base + i] + add;
      out[base + i] = v;
      pos[base + i] = v;
    }
  if (blockIdx.x == 0 && t == 0) out[N_NODES] = N_EDGES;
}

// XCD-confined scatter: 8 teams; team r handles dst range [r*12500, (r+1)*12500).
// blockIdx%8 maps to XCD on MI355X round-robin dispatch -> each csr line is
// dirtied by a single XCD's L2 (no cross-XCD line ping-pong -> no write amp).
// Correctness does NOT depend on that mapping: the 8 teams cover disjoint
// ranges and each team scans the whole edge list.
#define FILL_BPT 104                 // blocks per team
#define FILL_TEAM_THREADS (FILL_BPT * 256)

__global__ __launch_bounds__(256) void fill_kernel(const int* __restrict__ src,
                                                   const int* __restrict__ dst,
                                                   int* __restrict__ pos,
                                                   int* __restrict__ csr) {
  int r = blockIdx.x & 7;
  int rank = blockIdx.x >> 3;
  int lo = r * (N_NODES / 8);
  int hi = lo + (N_NODES / 8);
  int tid = rank * 256 + threadIdx.x;           // 0 .. FILL_TEAM_THREADS-1
  for (int gq = tid; gq < N_EDGES / 4; gq += FILL_TEAM_THREADS) {
    int i = gq * 4;
    v4i d4 = __builtin_nontemporal_load((const v4i*)&dst[i]);
    v4i s4 = __builtin_nontemporal_load((const v4i*)&src[i]);
    if (d4.x >= lo && d4.x < hi) { int p = atomicAdd(&pos[d4.x], 1); csr[p] = s4.x; }
    if (d4.y >= lo && d4.y < hi) { int p = atomicAdd(&pos[d4.y], 1); csr[p] = s4.y; }
    if (d4.z >= lo && d4.z < hi) { int p = atomicAdd(&pos[d4.z], 1); csr[p] = s4.z; }
    if (d4.w >= lo && d4.w < hi) { int p = atomicAdd(&pos[d4.w], 1); csr[p] = s4.w; }
  }
}

// S[v] = dv*(dv + sum of dinv[src]) == dv^2 + sum of edge weights
__global__ void ssum_kernel(const int* __restrict__ csr, const int* __restrict__ rowptr,
                            const float* __restrict__ dinv, float* __restrict__ Ssum) {
  int v = blockIdx.x * blockDim.x + threadIdx.x;
  if (v >= N_NODES) return;
  float dv = dinv[v];
  float s = dv;
  int e1 = rowptr[v + 1];
  for (int e = rowptr[v]; e < e1; ++e) s += dinv[csr[e]];
  Ssum[v] = dv * s;
}

// ---------------- per-layer GEMM: Hs[N,64] = dinv ⊙ (X[N,K] @ W[K,64]), bf16 out --------

__global__ __launch_bounds__(256) void gemm_kernel(
    const float* __restrict__ X, const float* __restrict__ W,
    const float* __restrict__ dinv, unsigned short* __restrict__ Hout, int K) {
  __shared__ float xs[64][81];
  __shared__ float ws[80][64];
  int t = threadIdx.x;
  int rowBase = blockIdx.x * 64;
  for (int i = t; i < K * 64; i += 256) ws[i >> 6][i & 63] = W[i];
  for (int i = t; i < 64 * K; i += 256) {
    int r = i / K, k = i - r * K;
    int row = rowBase + r;
    xs[r][k] = (row < N_NODES) ? X[(size_t)row * K + k] : 0.f;
  }
  __syncthreads();
  int ty = t >> 4, tx = t & 15;
  int r0 = ty * 4, c0 = tx * 4;
  float acc[4][4] = {};
  for (int k = 0; k < K; ++k) {
    float4 bq = *(const float4*)&ws[k][c0];
    float bv[4] = {bq.x, bq.y, bq.z, bq.w};
    float av[4] = {xs[r0][k], xs[r0 + 1][k], xs[r0 + 2][k], xs[r0 + 3][k]};
    #pragma unroll
    for (int i = 0; i < 4; ++i)
      #pragma unroll
      for (int j = 0; j < 4; ++j)
        acc[i][j] = fmaf(av[i], bv[j], acc[i][j]);
  }
  #pragma unroll
  for (int i = 0; i < 4; ++i) {
    int row = rowBase + r0 + i;
    if (row < N_NODES) {
      float dv = dinv[row];
      uint2 packed = make_uint2(bf2_pack(acc[i][0] * dv, acc[i][1] * dv),
                                bf2_pack(acc[i][2] * dv, acc[i][3] * dv));
      *(uint2*)&Hout[(size_t)row * HID + c0] = packed;
    }
  }
}

// ---------------- aggregation + relu + BN-stats ----------------
// z[v] = relu( dv*(Hs[v] + sum_in Hs[src]) + S[v]*c + b );  stats += (z, z^2)
// 4 feats/lane (uint2 = 4 bf16), 4 nodes/wave, 8x edge unroll

#define AGG_WAVES 8
#define AGG_NPN 2   // node iterations per quarter -> 64 nodes/block

__global__ __launch_bounds__(512) void agg_kernel(
    const unsigned short* __restrict__ Hs, const int* __restrict__ csr,
    const int* __restrict__ rowptr, const float* __restrict__ S,
    const float* __restrict__ dinv, const float* __restrict__ cvec,
    const float* __restrict__ bias, float* __restrict__ Z,
    float* __restrict__ stats) {
  int t = threadIdx.x;
  int wave = t >> 6, lane = t & 63;
  int q = lane >> 4, li = lane & 15;
  int f = li * 4;
  int nodeBase = blockIdx.x * (AGG_WAVES * 4 * AGG_NPN) + wave * (4 * AGG_NPN) + q;
  float4 cl = *(const float4*)&cvec[f];
  float4 bl = *(const float4*)&bias[f];
  float4 ssum = make_float4(0.f, 0.f, 0.f, 0.f);
  float4 ssq  = make_float4(0.f, 0.f, 0.f, 0.f);
  #pragma unroll
  for (int it = 0; it < AGG_NPN; ++it) {
    int v = nodeBase + 4 * it;
    if (v < N_NODES) {
      uint2 uv = *(const uint2*)&Hs[(size_t)v * HID + f];
      float4 acc = bf4_unpack(uv);
      int e0 = rowptr[v], e1 = rowptr[v + 1];
      int e = e0;
      for (; e + 8 <= e1; e += 8) {
        int s0 = csr[e + 0], s1 = csr[e + 1], s2 = csr[e + 2], s3 = csr[e + 3];
        int s4 = csr[e + 4], s5 = csr[e + 5], s6 = csr[e + 6], s7 = csr[e + 7];
        uint2 u0 = *(const uint2*)&Hs[(size_t)s0 * HID + f];
        uint2 u1 = *(const uint2*)&Hs[(size_t)s1 * HID + f];
        uint2 u2 = *(const uint2*)&Hs[(size_t)s2 * HID + f];
        uint2 u3 = *(const uint2*)&Hs[(size_t)s3 * HID + f];
        uint2 u4 = *(const uint2*)&Hs[(size_t)s4 * HID + f];
        uint2 u5 = *(const uint2*)&Hs[(size_t)s5 * HID + f];
        uint2 u6 = *(const uint2*)&Hs[(size_t)s6 * HID + f];
        uint2 u7 = *(const uint2*)&Hs[(size_t)s7 * HID + f];
        float4 h0 = bf4_unpack(u0), h1 = bf4_unpack(u1);
        float4 h2 = bf4_unpack(u2), h3 = bf4_unpack(u3);
        float4 h4 = bf4_unpack(u4), h5 = bf4_unpack(u5);
        float4 h6 = bf4_unpack(u6), h7 = bf4_unpack(u7);
        acc.x += (h0.x + h1.x) + (h2.x + h3.x) + (h4.x + h5.x) + (h6.x + h7.x);
        acc.y += (h0.y + h1.y) + (h2.y + h3.y) + (h4.y + h5.y) + (h6.y + h7.y);
        acc.z += (h0.z + h1.z) + (h2.z + h3.z) + (h4.z + h5.z) + (h6.z + h7.z);
        acc.w += (h0.w + h1.w) + (h2.w + h3.w) + (h4.w + h5.w) + (h6.w + h7.w);
      }
      for (; e + 2 <= e1; e += 2) {
        int s0 = csr[e + 0], s1 = csr[e + 1];
        uint2 u0 = *(const uint2*)&Hs[(size_t)s0 * HID + f];
        uint2 u1 = *(const uint2*)&Hs[(size_t)s1 * HID + f];
        float4 h0 = bf4_unpack(u0), h1 = bf4_unpack(u1);
        acc.x += h0.x + h1.x;
        acc.y += h0.y + h1.y;
        acc.z += h0.z + h1.z;
        acc.w += h0.w + h1.w;
      }
      if (e < e1) {
        int s0 = csr[e];
        float4 h0 = bf4_unpack(*(const uint2*)&Hs[(size_t)s0 * HID + f]);
        acc.x += h0.x; acc.y += h0.y; acc.z += h0.z; acc.w += h0.w;
      }
      float dv = dinv[v], sv = S[v];
      float4 z;
      z.x = fmaxf(fmaf(dv, acc.x, fmaf(sv, cl.x, bl.x)), 0.f);
      z.y = fmaxf(fmaf(dv, acc.y, fmaf(sv, cl.y, bl.y)), 0.f);
      z.z = fmaxf(fmaf(dv, acc.z, fmaf(sv, cl.z, bl.z)), 0.f);
      z.w = fmaxf(fmaf(dv, acc.w, fmaf(sv, cl.w, bl.w)), 0.f);
      *(float4*)&Z[(size_t)v * HID + f] = z;
      ssum.x += z.x; ssum.y += z.y; ssum.z += z.z; ssum.w += z.w;
      ssq.x += z.x * z.x; ssq.y += z.y * z.y; ssq.z += z.z * z.z; ssq.w += z.w * z.w;
    }
  }
  // reduce across the 4 quarters (same feats) via shuffles, then LDS across waves
  #pragma unroll
  for (int m = 16; m <= 32; m <<= 1) {
    ssum.x += __shfl_xor(ssum.x, m); ssum.y += __shfl_xor(ssum.y, m);
    ssum.z += __shfl_xor(ssum.z, m); ssum.w += __shfl_xor(ssum.w, m);
    ssq.x  += __shfl_xor(ssq.x,  m); ssq.y  += __shfl_xor(ssq.y,  m);
    ssq.z  += __shfl_xor(ssq.z,  m); ssq.w  += __shfl_xor(ssq.w,  m);
  }
  __shared__ float redS[AGG_WAVES][64];
  __shared__ float redQ[AGG_WAVES][64];
  if (q == 0) {
    *(float4*)&redS[wave][f] = ssum;
    *(float4*)&redQ[wave][f] = ssq;
  }
  __syncthreads();
  if (wave == 0) {
    float s = 0.f, qq = 0.f;
    #pragma unroll
    for (int i = 0; i < AGG_WAVES; ++i) { s += redS[i][lane]; qq += redQ[i][lane]; }
    float* sl = stats + (size_t)(blockIdx.x & (NSLICE - 1)) * 128;
    atomicAdd(&sl[lane], s);
    atomicAdd(&sl[64 + lane], qq);
  }
}

// ---------------- BN fold ----------------

__global__ __launch_bounds__(256) void prep_kernel(
    const float* __restrict__ stats, const float* __restrict__ g,
    const float* __restrict__ be, const float* __restrict__ Wnext,
    float* __restrict__ Wp, float* __restrict__ cvec,
    float* __restrict__ ab, int hasNext) {
  __shared__ float tmp[128];
  __shared__ float alpha[64];
  __shared__ float beta[64];
  int t = threadIdx.x;
  if (t < 128) {
    float s = 0.f;
    for (int i = 0; i < NSLICE; ++i) s += stats[(size_t)i * 128 + t];
    tmp[t] = s;
  }
  __syncthreads();
  if (t < 64) {
    float m = tmp[t] / (float)N_NODES;
    float var = tmp[64 + t] / (float)N_NODES - m * m;
    float a = g[t] * rsqrtf(var + BN_EPS);
    alpha[t] = a;
    float bt = be[t] - m * a;
    beta[t] = bt;
    ab[t] = a;
    ab[64 + t] = bt;
  }
  __syncthreads();
  if (hasNext) {
    for (int i = t; i < HID * HID; i += 256) Wp[i] = alpha[i >> 6] * Wnext[i];
    if (t < 64) {
      float c = 0.f;
      for (int k = 0; k < HID; ++k) c += beta[k] * Wnext[k * HID + t];
      cvec[t] = c;
    }
  }
}

// ---------------- pool ----------------

#define POOL_CH 32

__global__ __launch_bounds__(256) void pool_kernel(
    const float* __restrict__ Z, const int* __restrict__ batch,
    const float* __restrict__ ab, float* __restrict__ out) {
  int tid = blockIdx.x * blockDim.x + threadIdx.x;
  int w = tid >> 6, lane = tid & 63;
  int v0 = w * POOL_CH;
  if (v0 >= N_NODES) return;
  int v1 = min(N_NODES, v0 + POOL_CH);
  float a = ab[lane], b = ab[64 + lane];
  float acc = 0.f;
  int cur = batch[v0];
  for (int v = v0; v < v1; ++v) {
    int bg = batch[v];
    if (bg != cur) {
      atomicAdd(&out[(size_t)cur * HID + lane], acc);
      acc = 0.f;
      cur = bg;
    }
    acc = fmaf(Z[(size_t)v * HID + lane], a, acc + b);
  }
  atomicAdd(&out[(size_t)cur * HID + lane], acc);
}

// ---------------- launch ----------------

extern "C" void kernel_launch(void* const* d_in, const int* in_sizes, int n_in,
                              void* d_out, int out_size, void* d_ws, size_t ws_size,
                              hipStream_t stream) {
  const float* x    = (const float*)d_in[0];
  const int* src    = (const int*)d_in[1];
  const int* dst    = (const int*)d_in[2];
  const int* batch  = (const int*)d_in[3];
  const float* W[4]  = {(const float*)d_in[4], (const float*)d_in[8],
                        (const float*)d_in[12], (const float*)d_in[16]};
  const float* b[4]  = {(const float*)d_in[5], (const float*)d_in[9],
                        (const float*)d_in[13], (const float*)d_in[17]};
  const float* g[4]  = {(const float*)d_in[6], (const float*)d_in[10],
                        (const float*)d_in[14], (const float*)d_in[18]};
  const float* be[4] = {(const float*)d_in[7], (const float*)d_in[11],
                        (const float*)d_in[15], (const float*)d_in[19]};

  char* wsb = (char*)d_ws;
  size_t off = 0;
  auto alloc = [&](size_t bytes) -> void* {
    void* p = wsb + off;
    off += (bytes + 255) & ~(size_t)255;
    return p;
  };
  // zeroed region (one memset)
  int*   cnt    = (int*)  alloc((size_t)(N_NODES + 1) * 4);
  float* c0     = (float*)alloc(64 * 4);
  float* stats  = (float*)alloc((size_t)4 * NSLICE * 128 * 4);
  size_t zero_bytes = off;
  // non-zeroed
  float* Ssum   = (float*)alloc((size_t)N_NODES * 4);
  int*   rowptr = (int*)  alloc((size_t)(N_NODES + 1) * 4);
  int*   pos    = (int*)  alloc((size_t)N_NODES * 4);
  int*   bsum   = (int*)  alloc(128 * 4);
  float* dinv   = (float*)alloc((size_t)N_NODES * 4);
  int*   csr    = (int*)  alloc((size_t)N_EDGES * 4);
  unsigned short* Hb = (unsigned short*)alloc((size_t)N_NODES * HID * 2);
  float* Zb     = (float*)alloc((size_t)N_NODES * HID * 4);
  float* Wp     = (float*)alloc(HID * HID * 4);
  float* cv     = (float*)alloc(64 * 4);
  float* ab     = (float*)alloc(128 * 4);

  hipMemsetAsync(d_ws, 0, zero_bytes, stream);
  hipMemsetAsync(d_out, 0, (size_t)out_size * 4, stream);

  count_kernel<<<(N_EDGES / 4 + 255) / 256, 256, 0, stream>>>(dst, cnt);
  dinv_kernel<<<(N_NODES + 255) / 256, 256, 0, stream>>>(cnt, dinv);
  int nscan = (N_NODES + 1023) / 1024;
  scan1_kernel<<<nscan, 256, 0, stream>>>(cnt, rowptr, bsum);
  scan2_kernel<<<1, 64, 0, stream>>>(bsum, nscan);
  scan3_kernel<<<nscan, 256, 0, stream>>>(rowptr, bsum, pos);
  fill_kernel<<<8 * FILL_BPT, 256, 0, stream>>>(src, dst, pos, csr);
  ssum_kernel<<<(N_NODES + 255) / 256, 256, 0, stream>>>(csr, rowptr, dinv, Ssum);

  int gemmBlocks = (N_NODES + 63) / 64;
  int nodesPerAggBlock = AGG_WAVES * 4 * AGG_NPN;
  int aggBlocks = (N_NODES + nodesPerAggBlock - 1) / nodesPerAggBlock;

  // layer 1 (K=75, c=0)
  gemm_kernel<<<gemmBlocks, 256, 0, stream>>>(x, W[0], dinv, Hb, N_FEAT);
  agg_kernel<<<aggBlocks, 512, 0, stream>>>(Hb, csr, rowptr, Ssum, dinv, c0, b[0], Zb, stats);
  prep_kernel<<<1, 256, 0, stream>>>(stats, g[0], be[0], W[1], Wp, cv, ab, 1);

  // layers 2..4
  for (int l = 1; l < 4; ++l) {
    gemm_kernel<<<gemmBlocks, 256, 0, stream>>>(Zb, Wp, dinv, Hb, HID);
    agg_kernel<<<aggBlocks, 512, 0, stream>>>(Hb, csr, rowptr, Ssum, dinv, cv, b[l], Zb,
                                              stats + (size_t)l * NSLICE * 128);
    prep_kernel<<<1, 256, 0, stream>>>(stats + (size_t)l * NSLICE * 128, g[l], be[l],
                                       (l < 3) ? W[l + 1] : nullptr, Wp, cv, ab,
                                       (l < 3) ? 1 : 0);
  }

  int poolBlocks = (N_NODES + 4 * POOL_CH - 1) / (4 * POOL_CH);
  pool_kernel<<<poolBlocks, 256, 0, stream>>>(Zb, batch, ab, (float*)d_out);
}